// Round 1
// baseline (21146.906 us; speedup 1.0000x reference)
//
#include <hip/hip_runtime.h>
#include <cstdint>
#include <cstddef>

#define T_STEPS 100
#define IN_DIM  140
#define HDIM    256
#define G4      1024
#define RB      16
#define BTOT    4096
#define NBLK    (BTOT/RB)   // 256 blocks

#define K0      (IN_DIM + HDIM)   // 396
#define SZ_WT0  (K0*G4)           // 405504
#define K1      (2*HDIM)          // 512
#define SZ_WT1  (K1*G4)           // 524288
#define SZ_WTA  (HDIM*HDIM)       // 65536
#define OFF_WT0 0
#define OFF_WT1 (OFF_WT0 + SZ_WT0)     // 405504
#define OFF_WTA (OFF_WT1 + SZ_WT1)     // 929792
#define OFF_B0  (OFF_WTA + SZ_WTA)     // 995328
#define OFF_B1  (OFF_B0 + G4)          // 996352
#define WS_FLOATS (OFF_B1 + G4)        // 997376 floats ~= 3.99 MB

__device__ __forceinline__ float sigmoidf_(float x) {
    return 1.0f / (1.0f + __expf(-x));
}
__device__ __forceinline__ float tanhf_(float x) {
    // 1 - 2/(e^{2x}+1); saturates correctly at +-inf
    return 1.0f - 2.0f / (__expf(2.0f * x) + 1.0f);
}

__device__ __forceinline__ void load16(float* d, const float* s) {
    const float4* p = (const float4*)s;
    float4 a = p[0], b = p[1], c = p[2], e = p[3];
    d[0]=a.x; d[1]=a.y; d[2]=a.z;  d[3]=a.w;
    d[4]=b.x; d[5]=b.y; d[6]=b.z;  d[7]=b.w;
    d[8]=c.x; d[9]=c.y; d[10]=c.z; d[11]=c.w;
    d[12]=e.x; d[13]=e.y; d[14]=e.z; d[15]=e.w;
}

// Build transposed, gate-packed weights + folded biases in ws.
// Wt0 layout: ws[OFF_WT0 + (k*256 + j4)*4 + g] = W_l0[g*256 + j4][k]
//   where k<140 -> W_ih0, k>=140 -> W_hh0[k-140]. Same scheme for Wt1 (k<256 ih, else hh).
// WtA layout: ws[OFF_WTA + k*256 + j] = W_a1[j][k].
__global__ void prep(const float* __restrict__ Wih0, const float* __restrict__ Whh0,
                     const float* __restrict__ bih0, const float* __restrict__ bhh0,
                     const float* __restrict__ Wih1, const float* __restrict__ Whh1,
                     const float* __restrict__ bih1, const float* __restrict__ bhh1,
                     const float* __restrict__ Wa1,  float* __restrict__ ws)
{
    int idx = blockIdx.x * blockDim.x + threadIdx.x;
    if (idx >= WS_FLOATS) return;
    float v;
    if (idx < OFF_WT1) {
        int l = idx;
        int g = l & 3, j4 = (l >> 2) & 255, k = l >> 10;
        int j = g * HDIM + j4;
        v = (k < IN_DIM) ? Wih0[j * IN_DIM + k] : Whh0[j * HDIM + (k - IN_DIM)];
    } else if (idx < OFF_WTA) {
        int l = idx - OFF_WT1;
        int g = l & 3, j4 = (l >> 2) & 255, k = l >> 10;
        int j = g * HDIM + j4;
        v = (k < HDIM) ? Wih1[j * HDIM + k] : Whh1[j * HDIM + (k - HDIM)];
    } else if (idx < OFF_B0) {
        int l = idx - OFF_WTA;
        int j = l & 255, k = l >> 8;
        v = Wa1[j * HDIM + k];
    } else if (idx < OFF_B1) {
        int j = idx - OFF_B0;
        v = bih0[j] + bhh0[j];
    } else {
        int j = idx - OFF_B1;
        v = bih1[j] + bhh1[j];
    }
    ws[idx] = v;
}

__global__ __launch_bounds__(256, 1) void lstm_main(
    const float* __restrict__ x, const float* __restrict__ ws,
    const float* __restrict__ Wa2, const float* __restrict__ ba1,
    const float* __restrict__ ba2, float* __restrict__ out)
{
    __shared__ __align__(16) float xs[IN_DIM][RB];
    __shared__ __align__(16) float h0s[HDIM][RB];
    __shared__ __align__(16) float h1s[HDIM][RB];
    __shared__ __align__(16) float red[4][RB];

    const int tid  = threadIdx.x;
    const int jh   = tid;        // hidden unit owned by this thread (0..255)
    const int lane = tid & 63;
    const int wv   = tid >> 6;
    const int row0 = blockIdx.x * RB;

    const float4* W0 = (const float4*)(ws + OFF_WT0);
    const float4* W1 = (const float4*)(ws + OFF_WT1);
    const float*  WA = ws + OFF_WTA;
    const float*  b0 = ws + OFF_B0;
    const float*  b1 = ws + OFF_B1;

    float c0[RB], c1[RB];
    #pragma unroll
    for (int b = 0; b < RB; b++) { c0[b] = 0.f; c1[b] = 0.f; }
    for (int i = tid; i < HDIM * RB; i += 256) {
        (&h0s[0][0])[i] = 0.f;
        (&h1s[0][0])[i] = 0.f;
    }

    const float bi0 = b0[jh], bf0 = b0[jh + 256], bg0 = b0[jh + 512], bo0 = b0[jh + 768];
    const float bi1 = b1[jh], bf1 = b1[jh + 256], bg1 = b1[jh + 512], bo1 = b1[jh + 768];
    const float wa2  = Wa2[jh];
    const float ba1v = ba1[jh];
    const float ba2v = ba2[0];

    __syncthreads();

    for (int t = 0; t < T_STEPS; t++) {
        // ---- stage x_t into LDS (k-major) ----
        for (int i = tid; i < IN_DIM * RB; i += 256) {
            int b = i / IN_DIM, k = i - b * IN_DIM;
            xs[k][b] = x[(size_t)(row0 + b) * (T_STEPS * IN_DIM) + (size_t)t * IN_DIM + k];
        }
        __syncthreads();

        // ---- layer 0 gates ----
        float ai[RB], af[RB], ag[RB], ao[RB];
        #pragma unroll
        for (int b = 0; b < RB; b++) { ai[b] = bi0; af[b] = bf0; ag[b] = bg0; ao[b] = bo0; }

        #pragma unroll 2
        for (int k = 0; k < IN_DIM; k++) {
            float4 w = W0[k * HDIM + jh];
            float xq[RB]; load16(xq, &xs[k][0]);
            #pragma unroll
            for (int b = 0; b < RB; b++) {
                ai[b] = fmaf(w.x, xq[b], ai[b]);
                af[b] = fmaf(w.y, xq[b], af[b]);
                ag[b] = fmaf(w.z, xq[b], ag[b]);
                ao[b] = fmaf(w.w, xq[b], ao[b]);
            }
        }
        #pragma unroll 2
        for (int k = 0; k < HDIM; k++) {
            float4 w = W0[(IN_DIM + k) * HDIM + jh];
            float xq[RB]; load16(xq, &h0s[k][0]);
            #pragma unroll
            for (int b = 0; b < RB; b++) {
                ai[b] = fmaf(w.x, xq[b], ai[b]);
                af[b] = fmaf(w.y, xq[b], af[b]);
                ag[b] = fmaf(w.z, xq[b], ag[b]);
                ao[b] = fmaf(w.w, xq[b], ao[b]);
            }
        }

        float hn[RB];
        #pragma unroll
        for (int b = 0; b < RB; b++) {
            float ig = sigmoidf_(ai[b]);
            float fg = sigmoidf_(af[b]);
            float gg = tanhf_(ag[b]);
            float og = sigmoidf_(ao[b]);
            float c  = fmaf(fg, c0[b], ig * gg);
            c0[b] = c;
            hn[b] = og * tanhf_(c);
        }
        __syncthreads();   // all reads of old h0s done
        #pragma unroll
        for (int b = 0; b < RB; b++) h0s[jh][b] = hn[b];
        __syncthreads();   // new h0s visible

        // ---- layer 1 gates ----
        #pragma unroll
        for (int b = 0; b < RB; b++) { ai[b] = bi1; af[b] = bf1; ag[b] = bg1; ao[b] = bo1; }

        #pragma unroll 2
        for (int k = 0; k < HDIM; k++) {
            float4 w = W1[k * HDIM + jh];
            float xq[RB]; load16(xq, &h0s[k][0]);
            #pragma unroll
            for (int b = 0; b < RB; b++) {
                ai[b] = fmaf(w.x, xq[b], ai[b]);
                af[b] = fmaf(w.y, xq[b], af[b]);
                ag[b] = fmaf(w.z, xq[b], ag[b]);
                ao[b] = fmaf(w.w, xq[b], ao[b]);
            }
        }
        #pragma unroll 2
        for (int k = 0; k < HDIM; k++) {
            float4 w = W1[(HDIM + k) * HDIM + jh];
            float xq[RB]; load16(xq, &h1s[k][0]);
            #pragma unroll
            for (int b = 0; b < RB; b++) {
                ai[b] = fmaf(w.x, xq[b], ai[b]);
                af[b] = fmaf(w.y, xq[b], af[b]);
                ag[b] = fmaf(w.z, xq[b], ag[b]);
                ao[b] = fmaf(w.w, xq[b], ao[b]);
            }
        }

        #pragma unroll
        for (int b = 0; b < RB; b++) {
            float ig = sigmoidf_(ai[b]);
            float fg = sigmoidf_(af[b]);
            float gg = tanhf_(ag[b]);
            float og = sigmoidf_(ao[b]);
            float c  = fmaf(fg, c1[b], ig * gg);
            c1[b] = c;
            hn[b] = og * tanhf_(c);
        }
        __syncthreads();   // all reads of old h1s done
        #pragma unroll
        for (int b = 0; b < RB; b++) h1s[jh][b] = hn[b];
        __syncthreads();   // new h1s visible

        // ---- advantage MLP ----
        float ah[RB];
        #pragma unroll
        for (int b = 0; b < RB; b++) ah[b] = ba1v;
        #pragma unroll 2
        for (int k = 0; k < HDIM; k++) {
            float wk = WA[k * HDIM + jh];
            float xq[RB]; load16(xq, &h1s[k][0]);
            #pragma unroll
            for (int b = 0; b < RB; b++) ah[b] = fmaf(wk, xq[b], ah[b]);
        }
        #pragma unroll
        for (int b = 0; b < RB; b++) {
            float p = fmaxf(ah[b], 0.f) * wa2;
            #pragma unroll
            for (int m = 32; m >= 1; m >>= 1) p += __shfl_xor(p, m, 64);
            if (lane == 0) red[wv][b] = p;
        }
        __syncthreads();   // red ready
        if (tid < RB) {
            float o = red[0][tid] + red[1][tid] + red[2][tid] + red[3][tid] + ba2v;
            out[(size_t)t * BTOT + row0 + tid] = o;
        }
        // next-iteration hazards (xs overwrite, red overwrite) are protected by
        // the barrier after the next xs staging and the 4 barriers before next red write.
    }
}

extern "C" void kernel_launch(void* const* d_in, const int* in_sizes, int n_in,
                              void* d_out, int out_size, void* d_ws, size_t ws_size,
                              hipStream_t stream)
{
    const float* x    = (const float*)d_in[0];
    const float* Wih0 = (const float*)d_in[1];
    const float* Whh0 = (const float*)d_in[2];
    const float* bih0 = (const float*)d_in[3];
    const float* bhh0 = (const float*)d_in[4];
    const float* Wih1 = (const float*)d_in[5];
    const float* Whh1 = (const float*)d_in[6];
    const float* bih1 = (const float*)d_in[7];
    const float* bhh1 = (const float*)d_in[8];
    const float* Wa1  = (const float*)d_in[9];
    const float* ba1  = (const float*)d_in[10];
    const float* Wa2  = (const float*)d_in[11];
    const float* ba2  = (const float*)d_in[12];
    float* ws  = (float*)d_ws;
    float* out = (float*)d_out;

    hipLaunchKernelGGL(prep, dim3((WS_FLOATS + 255) / 256), dim3(256), 0, stream,
                       Wih0, Whh0, bih0, bhh0, Wih1, Whh1, bih1, bhh1, Wa1, ws);
    hipLaunchKernelGGL(lstm_main, dim3(NBLK), dim3(256), 0, stream,
                       x, ws, Wa2, ba1, ba2, out);
}